// Round 5
// baseline (461.982 us; speedup 1.0000x reference)
//
#include <hip/hip_runtime.h>

// Decoder_33208687133135 — fused Koopman decoder, MI355X (gfx950).
// Only the diagonal of s,t survives -> layer4 is a per-row dot with one W4
// column. ~292 GFLOP, f16 MFMA (absmax 0.0625 vs thr 0.2425).
//
// R8 post-mortem: 376 us, clean (VGPR 56, WRITE 0.5MB) but BANK_CONFLICT
// doubled to 4.17e7 (~68us DS stall): the b16 tanh->A-frag scatter's bank
// bits ignore lane bits 3,4 (the +256/+1024 terms) -> 32 lanes in 4 banks,
// 8-way x 384 writes/thread. Epilogue i=t>>3 reads same disease.
// R9: XOR bank-swizzle swz(e) = e ^ ((e>>8)&1)<<3 ^ ((e>>10)&1)<<4 over the
// whole ZA/HA address space. Write path folds to 4 per-lane bases
// (sbase + (rr^lane_m)*8) with immediate offsets + STATIC acc indices;
// read path folds to even/odd-ks bases (ks compile-time). Epilogue remapped
// lane-major (i=t&63, oct=t>>6) -> conflict-free reads, coalesced raw-W4
// fp32, LDS partial reduce. Spot-verified swizzle algebra at 3 points.

typedef _Float16 f16;
typedef _Float16 f16x8 __attribute__((ext_vector_type(8)));
typedef float f32x16 __attribute__((ext_vector_type(16)));

#define WPACK_PER_NET 589824
#define OFF_W1 0
#define OFF_W2 32768
#define OFF_W3 294912
#define OFF_W4T 557056
#define WPACK_BYTES (2u * WPACK_PER_NET * sizeof(f16))  // 2.36 MB

// ---------------- prologue: pack weights fp32 -> f16 blocked -------------
// B-fragment (32x32x16): B[k][n] held as n=lane&31, k=8*(lane>>5)+j.
// Frag (ks,ctg) covers k in [16ks,16ks+16), n in [32ctg,32ctg+32).
// Blocked flat index: ((ks*16 + ctg)*64 + lane)*8 + j.  (B is NOT swizzled
// — it never lives in LDS.)
__global__ void pack_weights(const float* __restrict__ sW1, const float* __restrict__ sW2,
                             const float* __restrict__ sW3, const float* __restrict__ sW4,
                             const float* __restrict__ tW1, const float* __restrict__ tW2,
                             const float* __restrict__ tW3, const float* __restrict__ tW4,
                             f16* __restrict__ dst) {
  int idx8 = (blockIdx.x * 256 + threadIdx.x) * 8;
  if (idx8 >= 2 * WPACK_PER_NET) return;
  int net = idx8 >= WPACK_PER_NET;
  int f = idx8 - net * WPACK_PER_NET;
  const float* W1 = net ? tW1 : sW1;
  const float* W2 = net ? tW2 : sW2;
  const float* W3 = net ? tW3 : sW3;
  const float* W4 = net ? tW4 : sW4;
  f16x8 o;
  if (f < OFF_W2) {               // W1: (64,512), ks<4
    int lane = (f >> 3) & 63, ctg = (f >> 9) & 15, ks = f >> 13;
    int r0 = ks * 16 + (lane >> 5) * 8, c = ctg * 32 + (lane & 31);
#pragma unroll
    for (int j = 0; j < 8; j++) o[j] = (f16)W1[(r0 + j) * 512 + c];
  } else if (f < OFF_W3) {        // W2: (512,512), ks<32
    int f2 = f - OFF_W2;
    int lane = (f2 >> 3) & 63, ctg = (f2 >> 9) & 15, ks = f2 >> 13;
    int r0 = ks * 16 + (lane >> 5) * 8, c = ctg * 32 + (lane & 31);
#pragma unroll
    for (int j = 0; j < 8; j++) o[j] = (f16)W2[(r0 + j) * 512 + c];
  } else if (f < OFF_W4T) {       // W3: (512,512)
    int f3 = f - OFF_W3;
    int lane = (f3 >> 3) & 63, ctg = (f3 >> 9) & 15, ks = f3 >> 13;
    int r0 = ks * 16 + (lane >> 5) * 8, c = ctg * 32 + (lane & 31);
#pragma unroll
    for (int j = 0; j < 8; j++) o[j] = (f16)W3[(r0 + j) * 512 + c];
  } else {                        // W4: (512,64) -> W4T[i][k] (kept; unused
    int f4 = f - OFF_W4T;         //  by R9 epilogue which reads raw W4)
    int i = f4 >> 9, k0 = f4 & 511;
#pragma unroll
    for (int j = 0; j < 8; j++) o[j] = (f16)W4[(k0 + j) * 64 + i];
  }
  *(f16x8*)(dst + net * WPACK_PER_NET + f) = o;
}

// A-fragment index (UNSWIZZLED) for a 64-row matrix, element (m,k):
// chunk = (k>>4)*2 + (m>>5); within-chunk lane = (m&31) + 32*((k>>3)&1).
__device__ __forceinline__ int aidx(int m, int k) {
  return ((k >> 4) * 2 + (m >> 5)) * 512 + ((m & 31) + 32 * ((k >> 3) & 1)) * 8 + (k & 7);
}

// Bank swizzle: XOR elem bits 3,4 (16B-slot group bits) with elem bits
// 8,10 (the lane-varying bits the scatter's bank index was blind to).
// Bijective; preserves 16B alignment of 8-elem runs.
__device__ __forceinline__ int swz(int e) {
  return e ^ (((e >> 8) & 1) << 3) ^ (((e >> 10) & 1) << 4);
}

// tanh(x) = 1 - 2/(exp(2x)+1). 6 VALU inst (2 trans-pipe). Saturates
// correctly at +/-inf, no clamp needed.
__device__ __forceinline__ float fast_tanh(float x) {
  float e = __expf(x + x);
  return fmaf(-2.0f, __builtin_amdgcn_rcpf(e + 1.0f), 1.0f);
}

// Load the wave's 2 B-fragments (64 cols = ctg 2w, 2w+1) for k-slice ks.
template <bool PACKED>
__device__ __forceinline__ void load_b(const f16* __restrict__ Wblk,
                                       const float* __restrict__ Wraw,
                                       int ks, int wave, int lane, f16x8* bdst) {
  if (PACKED) {
#pragma unroll
    for (int ct = 0; ct < 2; ct++)
      bdst[ct] = *(const f16x8*)(Wblk + ((ks * 16 + wave * 2 + ct) * 64 + lane) * 8);
  } else {
    int r0 = ks * 16 + (lane >> 5) * 8;
    int n0 = wave * 64 + (lane & 31);
#pragma unroll
    for (int ct = 0; ct < 2; ct++) {
      f16x8 v;
#pragma unroll
      for (int j = 0; j < 8; j++) v[j] = (f16)Wraw[(r0 + j) * 512 + n0 + ct * 32];
      bdst[ct] = v;
    }
  }
}

// One MLP layer: Hout(64x512) = tanh(Asrc(64xK) @ W(Kx512) + bias).
// 8 waves; wave w owns output cols [64w,64w+64) via 2x2 32x32 MFMA tiles.
// A-reads: swizzled elem' = ks*1024+mt*512 + (lane*8 ^ ((lane>>5)&1)<<3
// ^ (ks&1)<<4) -> two bases (even/odd ks), compile-time immediates.
// Writes: elem bits (8,10) == lane bits (3,4) exactly (no carries), so
// swz folds to 4 bases sbase+((rr^lane_m)<<3); acc index rq*4+rr STATIC.
template <int NS, bool PACKED, bool ALIASED>
__device__ __forceinline__ void mlp_layer(const f16* __restrict__ Wblk,
                                          const float* __restrict__ Wraw,
                                          const float* __restrict__ bias,
                                          const f16* Asrc, f16* Hout,
                                          int wave, int lane, int sbase,
                                          int lane8s, int lane_m) {
  f32x16 acc[2][2];
#pragma unroll
  for (int ct = 0; ct < 2; ct++) {
    float bv = bias[wave * 64 + ct * 32 + (lane & 31)];
#pragma unroll
    for (int mt = 0; mt < 2; mt++)
#pragma unroll
      for (int e = 0; e < 16; e++) acc[mt][ct][e] = bv;
  }

  const f16* abE = Asrc + lane8s;         // even ks base
  const f16* abO = Asrc + (lane8s ^ 16);  // odd ks base (bit4 flip)

  f16x8 bb[2][2];
  load_b<PACKED>(Wblk, Wraw, 0, wave, lane, bb[0]);
#pragma unroll
  for (int ks = 0; ks < NS; ks++) {
    if (ks + 1 < NS) load_b<PACKED>(Wblk, Wraw, ks + 1, wave, lane, bb[(ks + 1) & 1]);
    const f16* ab = ((ks & 1) ? abO : abE) + ks * 1024;  // imm: ks*2048B
    f16x8 a0 = *(const f16x8*)ab;
    f16x8 a1 = *(const f16x8*)(ab + 512);
#pragma unroll
    for (int ct = 0; ct < 2; ct++) {
      acc[0][ct] = __builtin_amdgcn_mfma_f32_32x32x16_f16(a0, bb[ks & 1][ct],
                                                          acc[0][ct], 0, 0, 0);
      acc[1][ct] = __builtin_amdgcn_mfma_f32_32x32x16_f16(a1, bb[ks & 1][ct],
                                                          acc[1][ct], 0, 0, 0);
    }
  }
  if (ALIASED) __syncthreads();  // all waves done reading Asrc (== Hout)

  // C/D layout (m74/m101): col = wave*64 + ct*32 + (lane&31),
  // row = mt*32 + (reg&3) + 8*(reg>>2) + 4*(lane>>5), reg = rq*4+rr.
  // Unswizzled target = sbase + ct*2048 + mt*512 + rq*64 + rr*8, with
  //   sbase = wave*4096 + ((lane>>4)&1)*1024 + ((lane>>3)&1)*256
  //           + (lane>>5)*32 + (lane&7)          (bits 3,4 of sbase = 0)
  // swz flips elem bits 3,4 by lane_m -> 4 bases, immediate offsets.
  // [verified: lane13/rr2 -> 285 == swz(277); banks now 16-distinct/instr]
#pragma unroll
  for (int rr = 0; rr < 4; rr++) {
    f16* hb = Hout + sbase + ((rr ^ lane_m) << 3);
#pragma unroll
    for (int mt = 0; mt < 2; mt++)
#pragma unroll
      for (int ct = 0; ct < 2; ct++)
#pragma unroll
        for (int rq = 0; rq < 4; rq++)
          hb[ct * 2048 + mt * 512 + rq * 64] =
              (f16)fast_tanh(acc[mt][ct][rq * 4 + rr]);
  }
  __syncthreads();
}

template <bool PACKED>
__global__ __launch_bounds__(512, 4) void decoder_main(
    const float* __restrict__ x, const float* __restrict__ koop,
    const f16* __restrict__ wpack,
    const float* __restrict__ sW1, const float* __restrict__ sW2,
    const float* __restrict__ sW3, const float* __restrict__ sW4,
    const float* __restrict__ tW1, const float* __restrict__ tW2,
    const float* __restrict__ tW3, const float* __restrict__ tW4,
    const float* __restrict__ sb1, const float* __restrict__ sb2,
    const float* __restrict__ sb3, const float* __restrict__ sb4,
    const float* __restrict__ tb1, const float* __restrict__ tb2,
    const float* __restrict__ tb3, const float* __restrict__ tb4,
    float* __restrict__ out) {
  __shared__ __align__(16) f16 ZA[4096];   // z tile, swizzled A-frag (8 KB)
  __shared__ __align__(16) f16 HA[32768];  // activations 64x512 (64 KB)
  __shared__ float pp[512];                // epilogue partials 8x64 (2 KB)
  __shared__ float redBuf[2][64];          // ds, dt
  // total ~75 KB; 512 thr, ~110 regs -> 2 blocks/CU (16 waves, 4/SIMD)

  const int b = blockIdx.x;
  const int t = threadIdx.x;
  const int wave = t >> 6, lane = t & 63;
  const int sbase = wave * 4096 + ((lane >> 4) & 1) * 1024 +
                    ((lane >> 3) & 1) * 256 + (lane >> 5) * 32 + (lane & 7);
  const int lane8s = (lane * 8) ^ (((lane >> 5) & 1) << 3);
  const int lane_m = ((lane >> 3) & 1) | (((lane >> 4) & 1) << 1);

  // Stage z = koopman[b]^T as swizzled f16 A-fragments.
  const float* kb = koop + b * 4096;
#pragma unroll
  for (int i = 0; i < 8; i++) {
    int flat = t + 512 * i;                 // coalesced fp32 read over d
    ZA[swz(aidx(flat & 63, flat >> 6))] = (f16)kb[flat];
  }
  __syncthreads();

  for (int net = 0; net < 2; net++) {
    const f16* wb = PACKED ? (wpack + net * WPACK_PER_NET) : (const f16*)0;
    const float* W1 = net ? tW1 : sW1;
    const float* W2 = net ? tW2 : sW2;
    const float* W3 = net ? tW3 : sW3;
    const float* W4 = net ? tW4 : sW4;
    const float* b1 = net ? tb1 : sb1;
    const float* b2 = net ? tb2 : sb2;
    const float* b3 = net ? tb3 : sb3;
    const float* b4 = net ? tb4 : sb4;
    // L1 reads ZA (never overwritten) -> no pre-write barrier needed.
    mlp_layer<4, PACKED, false>(PACKED ? wb + OFF_W1 : 0, W1, b1, ZA, HA,
                                wave, lane, sbase, lane8s, lane_m);
    mlp_layer<32, PACKED, true>(PACKED ? wb + OFF_W2 : 0, W2, b2, HA, HA,
                                wave, lane, sbase, lane8s, lane_m);
    mlp_layer<32, PACKED, true>(PACKED ? wb + OFF_W3 : 0, W3, b3, HA, HA,
                                wave, lane, sbase, lane8s, lane_m);

    // Diagonal epilogue: ds[i] = H3[i,:] . W4[:,i] + b4[i].
    // Lane-major rows (i = t&63) -> consecutive swizzled slots per read
    // instruction (conflict-free); W4 read raw fp32, lanes consecutive in
    // i -> coalesced. Wave `oct` covers k in [64*oct, 64*oct+64).
    {
      int i = lane, oct = wave;
      float p = 0.f;
#pragma unroll
      for (int q = 0; q < 8; q++) {
        int k0 = oct * 64 + q * 8;
        f16x8 hv = *(const f16x8*)&HA[swz(aidx(i, k0))];
#pragma unroll
        for (int j = 0; j < 8; j++)
          p += (float)hv[j] * W4[(k0 + j) * 64 + i];
      }
      pp[oct * 64 + i] = p;
    }
    __syncthreads();
    if (t < 64) {
      float s = b4[t];
#pragma unroll
      for (int o = 0; o < 8; o++) s += pp[o * 64 + t];
      redBuf[net][t] = s;
    }
    __syncthreads();  // pp reusable; redBuf[net] visible at the end
  }

  if (t < 64) {
    out[b * 64 + t] = (x[b * 64 + t] - redBuf[1][t]) * __expf(-redBuf[0][t]);
  }
}

extern "C" void kernel_launch(void* const* d_in, const int* in_sizes, int n_in,
                              void* d_out, int out_size, void* d_ws, size_t ws_size,
                              hipStream_t stream) {
  const float* x    = (const float*)d_in[0];
  const float* koop = (const float*)d_in[1];
  const float* sW1 = (const float*)d_in[2];  const float* sb1 = (const float*)d_in[3];
  const float* sW2 = (const float*)d_in[4];  const float* sb2 = (const float*)d_in[5];
  const float* sW3 = (const float*)d_in[6];  const float* sb3 = (const float*)d_in[7];
  const float* sW4 = (const float*)d_in[8];  const float* sb4 = (const float*)d_in[9];
  const float* tW1 = (const float*)d_in[10]; const float* tb1 = (const float*)d_in[11];
  const float* tW2 = (const float*)d_in[12]; const float* tb2 = (const float*)d_in[13];
  const float* tW3 = (const float*)d_in[14]; const float* tb3 = (const float*)d_in[15];
  const float* tW4 = (const float*)d_in[16]; const float* tb4 = (const float*)d_in[17];
  float* out = (float*)d_out;

  // Launch-invariant branch (ws_size constant across calls) -> graph-safe.
  // NEVER write past ws_size (R1: OOB pack corrupted harness allocations).
  if (ws_size >= (size_t)WPACK_BYTES) {
    f16* wpack = (f16*)d_ws;
    pack_weights<<<576, 256, 0, stream>>>(sW1, sW2, sW3, sW4, tW1, tW2, tW3, tW4, wpack);
    decoder_main<true><<<2048, 512, 0, stream>>>(
        x, koop, wpack, sW1, sW2, sW3, sW4, tW1, tW2, tW3, tW4,
        sb1, sb2, sb3, sb4, tb1, tb2, tb3, tb4, out);
  } else {
    decoder_main<false><<<2048, 512, 0, stream>>>(
        x, koop, (const f16*)0, sW1, sW2, sW3, sW4, tW1, tW2, tW3, tW4,
        sb1, sb2, sb3, sb4, tb1, tb2, tb3, tb4, out);
  }
}